// Round 10
// baseline (1824.292 us; speedup 1.0000x reference)
//
#include <hip/hip_runtime.h>

// Furthest Point Sampling, B=8, C=3, N=65536, NUM_POINTS=1024.
//
// R10 = R9 + (a) fast-path exchange line moved into d_out, (b) DPP reductions.
//
// Why (a): R3/R6/R8/R9 are invariant at ~1.7us/iter regardless of protocol.
// Hypothesis: d_ws is fine-grained (L2-uncached MTYPE) memory, so every
// exchange was forced through the Infinity Cache no matter what. d_out is
// ordinary device memory (L2-cached). Line A (fast path) now lives in the
// first 2KB of each batch's 12KB output span; line B (agent/IC, authoritative)
// stays in d_ws and is merged into the poll from round 3 -> progress never
// depends on placement or memory type. The final gather overwrites d_out only
// after a release/acquire DONE handshake (each block release-stores a DONE tag
// after its last slot store; slice 0 acquire-polls all 16 DONE words), so no
// slot store can land after gather data is written.
//
// Why (b): the three u64 shuffle butterflies were ~24 dependent DS ops
// (~600-700cy) on the serial chain. Replaced with the canonical gfx9 6-step
// DPP max sequence (VALU speed; old=0 is a valid identity since keys > 0),
// result broadcast via readlane(63).
//
// Placement: measured via s_getreg(HW_REG_XCC_ID); first 16 registrants on
// XCD j own batch j; spares cover vacancies (bounded wait, no deadlock);
// spare-covered slices ride the IC fallback line. Per iteration: ONE barrier,
// single poller wave, LDS mailbox fanout, tagged depth-16 slot regions
// (0xAA poison = tag 0xAAAA never matches it < 1024 -> no memset).
//
// Key packing (idx < 65536): dist_bits(32) | (0xFFFF - idx)(16) | it(16).
// Max key = max dist, tie -> smaller index == jnp.argmax first-occurrence.
// Distance math: __fmul_rn/__fadd_rn (no FMA contraction) to bit-match numpy.

namespace {

constexpr int kB = 8;
constexpr int kN = 65536;
constexpr int kNP = 1024;
constexpr int kPB = 16;                      // slices (blocks) per batch
constexpr int kThreads = 256;
constexpr int kPPT = kN / (kPB * kThreads);  // 16 points per thread
constexpr int kGrp = kPPT / 4;               // 4 float4 groups
constexpr int kWaves = kThreads / 64;        // 4
constexpr int kRgn = 16;                     // region reuse depth (skew < 2)
constexpr int kBlocks = 256;
constexpr unsigned kDoneTag = 0xD07Eu;

__device__ __forceinline__ unsigned long long u64max(unsigned long long a,
                                                     unsigned long long b) {
  return a > b ? a : b;
}

template <int CTRL>
__device__ __forceinline__ unsigned long long dpp_u64_zero(unsigned long long v) {
  const unsigned lo =
      (unsigned)__builtin_amdgcn_update_dpp(0, (int)(unsigned)v, CTRL, 0xf, 0xf, false);
  const unsigned hi =
      (unsigned)__builtin_amdgcn_update_dpp(0, (int)(unsigned)(v >> 32), CTRL, 0xf, 0xf, false);
  return ((unsigned long long)hi << 32) | lo;
}

// 64-lane max reduce via DPP (keys > 0, so old=0 is an identity), then
// broadcast lane 63's result to all lanes. VALU-speed: no LDS/DS ops.
__device__ __forceinline__ unsigned long long wave_max_u64(unsigned long long v) {
  v = u64max(v, dpp_u64_zero<0x111>(v));  // row_shr:1
  v = u64max(v, dpp_u64_zero<0x112>(v));  // row_shr:2
  v = u64max(v, dpp_u64_zero<0x114>(v));  // row_shr:4
  v = u64max(v, dpp_u64_zero<0x118>(v));  // row_shr:8
  v = u64max(v, dpp_u64_zero<0x142>(v));  // row_bcast:15
  v = u64max(v, dpp_u64_zero<0x143>(v));  // row_bcast:31
  const unsigned lo = (unsigned)__builtin_amdgcn_readlane((int)(unsigned)v, 63);
  const unsigned hi = (unsigned)__builtin_amdgcn_readlane((int)(unsigned)(v >> 32), 63);
  return ((unsigned long long)hi << 32) | lo;
}

// sc0 load/store: bypass L1, served by the XCD's shared L2.
__device__ __forceinline__ unsigned long long load_l2(const unsigned long long* p) {
  unsigned long long v;
  asm volatile("global_load_dwordx2 %0, %1, off sc0\n\ts_waitcnt vmcnt(0)"
               : "=v"(v)
               : "v"(p)
               : "memory");
  return v;
}

__device__ __forceinline__ void store_l2(unsigned long long* p, unsigned long long v) {
  asm volatile("global_store_dwordx2 %0, %1, off sc0" ::"v"(p), "v"(v) : "memory");
}

__global__ __launch_bounds__(kThreads) void fps_kernel(const float* __restrict__ pts,
                                                       float* __restrict__ out,
                                                       unsigned long long* __restrict__ slotsB,
                                                       unsigned long long* __restrict__ done,
                                                       unsigned* __restrict__ ctrl) {
  // ctrl: [0:8) per-XCD registration counters, [8] done count, [9] spare rank.
  const int tid = threadIdx.x;
  const int lane = tid & 63;
  const int wave = tid >> 6;

  __shared__ int s_batch, s_slice;
  __shared__ unsigned long long s_wkey[kWaves];
  __shared__ unsigned s_win[2];  // parity mailbox: (wi << 16) | it
  __shared__ int s_hist[kNP];

  if (tid == 0) {
    unsigned xcc;
    asm volatile("s_getreg_b32 %0, hwreg(HW_REG_XCC_ID)" : "=s"(xcc));
    const int home = (int)(xcc & 7u);
    int batch = -1, slice = -1;
    const int pos = (int)atomicAdd(&ctrl[home], 1u);
    if (pos < kPB) {
      batch = home;
      slice = pos;
    }
    __hip_atomic_fetch_add(&ctrl[8], 1u, __ATOMIC_RELEASE, __HIP_MEMORY_SCOPE_AGENT);
    if (batch < 0) {
      while (__hip_atomic_load(&ctrl[8], __ATOMIC_ACQUIRE, __HIP_MEMORY_SCOPE_AGENT) <
             (unsigned)kBlocks) {
        __builtin_amdgcn_s_sleep(8);
      }
      int need = (int)atomicAdd(&ctrl[9], 1u);
      for (int j = 0; j < kB; ++j) {
        int have = (int)__hip_atomic_load(&ctrl[j], __ATOMIC_RELAXED, __HIP_MEMORY_SCOPE_AGENT);
        have = have > kPB ? kPB : have;
        const int vac = kPB - have;
        if (need < vac) {
          batch = j;
          slice = have + need;
          break;
        }
        need -= vac;
      }
    }
    s_batch = batch;
    s_slice = slice;
    s_win[0] = 0xFFFFFFFFu;  // tag 0xFFFF never matches it < 1024
    s_win[1] = 0xFFFFFFFFu;
  }
  __syncthreads();

  const int batch = s_batch;
  const int slice = s_slice;
  if (batch < 0) return;  // unneeded spare

  const float* __restrict__ xb = pts + (size_t)batch * 3 * kN;
  const float* __restrict__ yb = xb + kN;
  const float* __restrict__ zb = xb + 2 * kN;

  // Line A (L2 fast path) lives in this batch's d_out span (2KB of 12KB).
  unsigned long long* const lineA = (unsigned long long*)(out + (size_t)batch * 3 * kNP);
  unsigned long long* const lineB = slotsB + (size_t)batch * kRgn * kPB;

  // Register-resident coords: block owns [slice*4096, slice*4096+4096).
  const int sbase = slice * (kThreads * kPPT);
  const int base0 = sbase + tid * 4;
  float px[kPPT], py[kPPT], pz[kPPT], dist[kPPT];
#pragma unroll
  for (int g = 0; g < kGrp; ++g) {
    const int base = base0 + g * (kThreads * 4);
    const float4 vx = *reinterpret_cast<const float4*>(xb + base);
    const float4 vy = *reinterpret_cast<const float4*>(yb + base);
    const float4 vz = *reinterpret_cast<const float4*>(zb + base);
    px[g * 4 + 0] = vx.x; px[g * 4 + 1] = vx.y; px[g * 4 + 2] = vx.z; px[g * 4 + 3] = vx.w;
    py[g * 4 + 0] = vy.x; py[g * 4 + 1] = vy.y; py[g * 4 + 2] = vy.z; py[g * 4 + 3] = vy.w;
    pz[g * 4 + 0] = vz.x; pz[g * 4 + 1] = vz.y; pz[g * 4 + 2] = vz.z; pz[g * 4 + 3] = vz.w;
  }
#pragma unroll
  for (int k = 0; k < kPPT; ++k) dist[k] = 1e10f;

  // Seed: index 0 (uniform broadcast load).
  float qx = xb[0], qy = yb[0], qz = zb[0];

  for (int it = 1; it < kNP; ++it) {
    // --- update dists + per-thread argmax (ascending index, strict '>') ---
    float bd = -1.0f;
    int bi = 0;
#pragma unroll
    for (int g = 0; g < kGrp; ++g) {
#pragma unroll
      for (int j = 0; j < 4; ++j) {
        const int k = g * 4 + j;
        const float dx = px[k] - qx;
        const float dy = py[k] - qy;
        const float dz = pz[k] - qz;
        const float ss =
            __fadd_rn(__fadd_rn(__fmul_rn(dx, dx), __fmul_rn(dy, dy)), __fmul_rn(dz, dz));
        const float nd = fminf(dist[k], ss);
        dist[k] = nd;
        if (nd > bd) {
          bd = nd;
          bi = base0 + g * (kThreads * 4) + j;
        }
      }
    }

    // key: dist(32) | (0xFFFF - idx)(16) | it(16)  -- tag self-validates slots.
    unsigned long long key = ((unsigned long long)__float_as_uint(bd) << 32) |
                             ((unsigned long long)(0xFFFFu - (unsigned)bi) << 16) |
                             (unsigned long long)(unsigned)it;

    // --- wave max via DPP (VALU speed, uniform result) ---
    key = wave_max_u64(key);
    if (lane == 0) s_wkey[wave] = key;
    __syncthreads();  // the only barrier in the iteration

    int wi;
    if (wave == 0) {
      // --- block reduce over 4 wave keys (DPP; redundant lanes are copies) ---
      unsigned long long bk = s_wkey[lane & (kWaves - 1)];
      bk = wave_max_u64(bk);

      const int rg = (it & (kRgn - 1)) * kPB;
      if (lane == 0) {
        store_l2(lineA + rg + slice, bk);  // fast path: L2-cached d_out
        __hip_atomic_store(lineB + rg + slice, bk, __ATOMIC_RELAXED,
                           __HIP_MEMORY_SCOPE_AGENT);  // authoritative: IC
      }

      // --- poll line A from round 0; merge IC line B from round 3 ---
      unsigned long long w;
      int round = 0;
      for (;;) {
        unsigned long long a = load_l2(lineA + rg + (lane & (kPB - 1)));
        bool ok = (unsigned)(a & 0xFFFFull) == (unsigned)it;
        if (round >= 3 && !ok) {
          const unsigned long long fb = __hip_atomic_load(
              lineB + rg + (lane & (kPB - 1)), __ATOMIC_RELAXED, __HIP_MEMORY_SCOPE_AGENT);
          if ((unsigned)(fb & 0xFFFFull) == (unsigned)it) {
            a = fb;
            ok = true;
          }
        }
        if (__all(ok)) {
          w = a;
          break;
        }
        ++round;
      }
      // --- slot reduce (DPP; lanes hold slot lane&15, 4x redundant copies) ---
      w = wave_max_u64(w);
      wi = (int)(0xFFFFu - ((unsigned)(w >> 16) & 0xFFFFu));
      if (lane == 0) {
        s_hist[it] = wi;
        __hip_atomic_store(&s_win[it & 1], ((unsigned)wi << 16) | (unsigned)it,
                           __ATOMIC_RELAXED, __HIP_MEMORY_SCOPE_WORKGROUP);
      }
    } else {
      // --- non-leader waves: spin on the LDS mailbox (no global traffic) ---
      unsigned v;
      do {
        v = __hip_atomic_load(&s_win[it & 1], __ATOMIC_RELAXED, __HIP_MEMORY_SCOPE_WORKGROUP);
      } while ((v & 0xFFFFu) != (unsigned)it);
      wi = (int)(v >> 16);
    }

    // Winner coords: uniform scalar loads (points are L2-resident).
    const int wiu = __builtin_amdgcn_readfirstlane(wi);
    qx = xb[wiu];
    qy = yb[wiu];
    qz = zb[wiu];
  }

  __syncthreads();  // s_hist complete and visible block-wide

  // --- DONE handshake: release-publish after ALL this block's slot stores ---
  if (tid == 0) {
    // Release ordering drains prior stores (incl. inline-asm sc0 stores) to
    // the agent coherence point before the DONE word becomes visible.
    __hip_atomic_store(&done[batch * kPB + slice],
                       ((unsigned long long)slice << 32) | kDoneTag, __ATOMIC_RELEASE,
                       __HIP_MEMORY_SCOPE_AGENT);
  }

  // --- gather: out[b][c][j] = points[b][c][idx_j]; slice-0 block per batch ---
  if (slice == 0) {
    if (wave == 0) {
      // Acquire-poll all 16 DONE words: afterwards no peer store to d_out can
      // be ordered after our gather writes.
      unsigned long long d;
      do {
        d = __hip_atomic_load(&done[batch * kPB + (lane & (kPB - 1))], __ATOMIC_ACQUIRE,
                              __HIP_MEMORY_SCOPE_AGENT);
      } while (!__all((unsigned)(d & 0xFFFFull) == kDoneTag));
    }
    __syncthreads();

    float* __restrict__ ob = out + (size_t)batch * 3 * kNP;
    for (int j = tid; j < kNP; j += kThreads) {
      const int id = (j == 0) ? 0 : s_hist[j];
      ob[j] = xb[id];
      ob[kNP + j] = yb[id];
      ob[2 * kNP + j] = zb[id];
    }
  }
}

}  // namespace

extern "C" void kernel_launch(void* const* d_in, const int* in_sizes, int n_in,
                              void* d_out, int out_size, void* d_ws, size_t ws_size,
                              hipStream_t stream) {
  (void)in_sizes;
  (void)n_in;
  (void)out_size;
  (void)ws_size;
  const float* pts = (const float*)d_in[0];
  float* out = (float*)d_out;
  // ws: [0,64) ctrl (zeroed), [1024, 1024+16K) line B slots, [32768, +1K) DONE
  // words. Slot/DONE words are tag-validated (0xAA poison -> 0xAAAA never
  // matches it < 1024 or 0xD07E) -> no memset beyond the 64B ctrl block.
  unsigned* ctrl = (unsigned*)d_ws;
  unsigned long long* slotsB = (unsigned long long*)((char*)d_ws + 1024);
  unsigned long long* done = (unsigned long long*)((char*)d_ws + 32768);
  hipMemsetAsync(d_ws, 0, 64, stream);
  fps_kernel<<<dim3(kBlocks), dim3(kThreads), 0, stream>>>(pts, out, slotsB, done, ctrl);
}